// Round 13
// baseline (251.484 us; speedup 1.0000x reference)
//
#include <hip/hip_runtime.h>
#include <hip/hip_bf16.h>
#include <hip/hip_cooperative_groups.h>

#define NEG_SLOPE 0.2f

namespace cg = cooperative_groups;

typedef float f32x4 __attribute__((ext_vector_type(4)));

// ---------------------------------------------------------------------------
// Folded 64-lane reduction (6 shuffles) — proven R5.
// ---------------------------------------------------------------------------
__device__ __forceinline__ float fold_reduce(float sib, float sjb,
                                             float sip, float sjp,
                                             bool hiB, bool hiJ) {
    float g1 = hiB ? sib : sip;
    float r1 = __shfl_xor(g1, 16);
    float acc_i = (hiB ? sip : sib) + r1;
    float g2 = hiB ? sjb : sjp;
    float r2 = __shfl_xor(g2, 16);
    float acc_j = (hiB ? sjp : sjb) + r2;
    float g3 = hiJ ? acc_i : acc_j;
    float r3 = __shfl_xor(g3, 8);
    float acc = (hiJ ? acc_j : acc_i) + r3;
    acc += __shfl_xor(acc, 4);
    acc += __shfl_xor(acc, 2);
    acc += __shfl_xor(acc, 1);
    return acc;
}

__device__ __forceinline__ float dot4(const f32x4 z, const f32x4 v) {
    return z.x * v.x + z.y * v.y + z.z * v.z + z.w * v.w;
}

__device__ __forceinline__ float lrelu(float x) {
    return x >= 0.f ? x : NEG_SLOPE * x;
}

__device__ __forceinline__ float edge_score(const f32x4 ts, const f32x4 td,
                                            float w0, float w1) {
    const float sb = 0.5f * (lrelu(ts.x + td.y) + lrelu(td.x + ts.y));
    const float sp = 0.5f * (lrelu(ts.z + td.w) + lrelu(td.z + ts.w));
    const float sc = w0 * sb + w1 * sp;            // TAU_MRF == 1
    return 1.f / (1.f + __expf(-sc));
}

// ---------------------------------------------------------------------------
// Cooperative single kernel: 1024 blocks x 256 threads.
// __launch_bounds__(256,8): 8 waves/EU -> VGPR<=64 -> 8 blocks/CU occupancy
// -> cooperative residency limit 2048 blocks; we ask 1024 (2x margin).
//   phase 0: per-block v-fold (vsh, 2KB LDS; W is L2-resident after first
//            few blocks, all 1024 prologues run concurrently)
//   phase 1: node scores -> fp32 tab (R12-proven wave-pair loop)
//   grid.sync()
//   phase 2: edge scores (R6-proven, 2 edges/thread)
// ---------------------------------------------------------------------------
__global__ void __launch_bounds__(256, 8) coop_all_kernel(
        const float* __restrict__ W_b,
        const float* __restrict__ W_p,
        const float* __restrict__ a_b,
        const float* __restrict__ a_p,
        const f32x4* __restrict__ zb4,
        const f32x4* __restrict__ zp4,
        const int*   __restrict__ src,
        const int*   __restrict__ dst,
        const float* __restrict__ gamma_b,
        const float* __restrict__ gamma_p,
        float*       __restrict__ out,
        float*       __restrict__ tab,     // [n_nodes][4] fp32
        int n_nodes, int n_edges) {
    __shared__ float vsh[4][128];

    const int tid = threadIdx.x;

    // ---- phase 0: v prologue (R2-proven form) ----
    {
        const int p  = tid & 127;
        const int ch = tid >> 7;
        const float* W = ch ? W_p : W_b;
        const float* a = ch ? a_p : a_b;
        float acc1 = 0.f, acc2 = 0.f;
        #pragma unroll
        for (int d = 0; d < 64; ++d) {
            const float w = W[d * 128 + p];
            acc1 += w * a[d];
            acc2 += w * a[64 + d];
        }
        vsh[2 * ch + 0][p] = acc1;
        vsh[2 * ch + 1][p] = acc2;
    }
    __syncthreads();

    // ---- phase 1: node scores ----
    {
        const int lane = tid & 63;
        const int h    = lane >> 5;
        const int c    = lane & 31;
        const int wave   = (blockIdx.x * blockDim.x + tid) >> 6;
        const int nwaves = (gridDim.x * blockDim.x) >> 6;   // 4096
        const int npairs = (n_nodes + 1) >> 1;

        const f32x4 v1b = *reinterpret_cast<const f32x4*>(&vsh[0][4 * c]);
        const f32x4 v2b = *reinterpret_cast<const f32x4*>(&vsh[1][4 * c]);
        const f32x4 v1p = *reinterpret_cast<const f32x4*>(&vsh[2][4 * c]);
        const f32x4 v2p = *reinterpret_cast<const f32x4*>(&vsh[3][4 * c]);

        const bool hiB = (c & 16) != 0;
        const bool hiJ = (c & 8)  != 0;
        const bool wr  = (c & 7) == 0;
        const int  comp = c >> 3;

        for (int pr = wave; pr < npairs; pr += 2 * nwaves) {
            const int pr2 = pr + nwaves;
            int node1 = 2 * pr + h;
            const bool valid1 = node1 < n_nodes;
            if (!valid1) node1 = n_nodes - 1;
            const f32x4 zb1 = zb4[(size_t)node1 * 32 + c];
            const f32x4 zp1 = zp4[(size_t)node1 * 32 + c];
            int node2 = 2 * pr2 + h;
            const bool run2 = pr2 < npairs;
            bool valid2 = run2 && (node2 < n_nodes);
            if (!valid2) node2 = n_nodes - 1;
            const f32x4 zb2 = zb4[(size_t)node2 * 32 + c];
            const f32x4 zp2 = zp4[(size_t)node2 * 32 + c];

            float acc1 = fold_reduce(dot4(zb1, v1b), dot4(zb1, v2b),
                                     dot4(zp1, v1p), dot4(zp1, v2p), hiB, hiJ);
            if (wr && valid1) tab[(size_t)node1 * 4 + comp] = acc1;

            float acc2 = fold_reduce(dot4(zb2, v1b), dot4(zb2, v2b),
                                     dot4(zp2, v1p), dot4(zp2, v2p), hiB, hiJ);
            if (wr && valid2) tab[(size_t)node2 * 4 + comp] = acc2;
        }
    }

    // ---- publish tab across XCD L2s, grid-wide sync ----
    __threadfence();
    cg::this_grid().sync();

    // ---- phase 2: edge scores ----
    {
        const float gb = *gamma_b;
        const float gp = *gamma_p;
        const float w0 = 1.f / (1.f + __expf(gp - gb));
        const float w1 = 1.f - w0;

        const f32x4* tab4 = (const f32x4*)tab;
        const int n_half = n_edges >> 1;
        const int stride = gridDim.x * blockDim.x;
        const int gid    = blockIdx.x * blockDim.x + tid;

        const int2* src2 = (const int2*)src;
        const int2* dst2 = (const int2*)dst;
        float2*     out2 = (float2*)out;

        for (int i = gid; i < n_half; i += stride) {
            const int2 s = src2[i];
            const int2 d = dst2[i];
            const f32x4 ts0 = tab4[s.x];
            const f32x4 td0 = tab4[d.x];
            const f32x4 ts1 = tab4[s.y];
            const f32x4 td1 = tab4[d.y];
            float2 r;
            r.x = edge_score(ts0, td0, w0, w1);
            r.y = edge_score(ts1, td1, w0, w1);
            out2[i] = r;
        }
        const int tail_base = n_half << 1;
        for (int e = tail_base + gid; e < n_edges; e += stride) {
            out[e] = edge_score(tab4[src[e]], tab4[dst[e]], w0, w1);
        }
    }
}

// ---------------------------------------------------------------------------
// Fallback path — EXACT R12 two-dispatch pipeline (proven 36.5 us).
// ---------------------------------------------------------------------------
__global__ void __launch_bounds__(1024) fused_node_kernel(
        const float* __restrict__ W_b,
        const float* __restrict__ W_p,
        const float* __restrict__ a_b,
        const float* __restrict__ a_p,
        const f32x4* __restrict__ zb4,
        const f32x4* __restrict__ zp4,
        float*       __restrict__ tab,
        int n_nodes) {
    __shared__ float vsh[4][128];
    __shared__ float psh[1024];

    const int tid = threadIdx.x;
    {
        const int q   = tid >> 9;
        const int r   = tid & 511;
        const int vec = r >> 7;
        const int p   = r & 127;
        const float* W = (vec >= 2) ? W_p : W_b;
        const float* a = ((vec >= 2) ? a_p : a_b) + (vec & 1) * 64 + 32 * q;
        const float* Wc = W + (32 * q) * 128 + p;
        float acc = 0.f;
        #pragma unroll
        for (int k = 0; k < 32; ++k)
            acc += Wc[k * 128] * a[k];
        psh[tid] = acc;
    }
    __syncthreads();
    if (tid < 512)
        vsh[tid >> 7][tid & 127] = psh[tid] + psh[512 + tid];
    __syncthreads();

    const int lane = tid & 63;
    const int h    = lane >> 5;
    const int c    = lane & 31;
    const int wave   = (blockIdx.x * blockDim.x + tid) >> 6;
    const int nwaves = (gridDim.x * blockDim.x) >> 6;
    const int npairs = (n_nodes + 1) >> 1;

    const f32x4 v1b = *reinterpret_cast<const f32x4*>(&vsh[0][4 * c]);
    const f32x4 v2b = *reinterpret_cast<const f32x4*>(&vsh[1][4 * c]);
    const f32x4 v1p = *reinterpret_cast<const f32x4*>(&vsh[2][4 * c]);
    const f32x4 v2p = *reinterpret_cast<const f32x4*>(&vsh[3][4 * c]);

    const bool hiB = (c & 16) != 0;
    const bool hiJ = (c & 8)  != 0;
    const bool wr  = (c & 7) == 0;
    const int  comp = c >> 3;

    for (int pr = wave; pr < npairs; pr += 2 * nwaves) {
        const int pr2 = pr + nwaves;
        int node1 = 2 * pr + h;
        const bool valid1 = node1 < n_nodes;
        if (!valid1) node1 = n_nodes - 1;
        const f32x4 zb1 = zb4[(size_t)node1 * 32 + c];
        const f32x4 zp1 = zp4[(size_t)node1 * 32 + c];
        int node2 = 2 * pr2 + h;
        const bool run2 = pr2 < npairs;
        bool valid2 = run2 && (node2 < n_nodes);
        if (!valid2) node2 = n_nodes - 1;
        const f32x4 zb2 = zb4[(size_t)node2 * 32 + c];
        const f32x4 zp2 = zp4[(size_t)node2 * 32 + c];

        float acc1 = fold_reduce(dot4(zb1, v1b), dot4(zb1, v2b),
                                 dot4(zp1, v1p), dot4(zp1, v2p), hiB, hiJ);
        if (wr && valid1) tab[(size_t)node1 * 4 + comp] = acc1;

        float acc2 = fold_reduce(dot4(zb2, v1b), dot4(zb2, v2b),
                                 dot4(zp2, v1p), dot4(zp2, v2p), hiB, hiJ);
        if (wr && valid2) tab[(size_t)node2 * 4 + comp] = acc2;
    }
}

__global__ void __launch_bounds__(256) edge_scores_kernel(
        const int*   __restrict__ src,
        const int*   __restrict__ dst,
        const f32x4* __restrict__ tab,
        const float* __restrict__ gamma_b,
        const float* __restrict__ gamma_p,
        float*       __restrict__ out,
        int n_edges) {
    const float gb = *gamma_b;
    const float gp = *gamma_p;
    const float w0 = 1.f / (1.f + __expf(gp - gb));
    const float w1 = 1.f - w0;

    const int n_half = n_edges >> 1;
    const int stride = gridDim.x * blockDim.x;
    const int gid    = blockIdx.x * blockDim.x + threadIdx.x;

    const int2* src2 = (const int2*)src;
    const int2* dst2 = (const int2*)dst;
    float2*     out2 = (float2*)out;

    for (int i = gid; i < n_half; i += stride) {
        const int2 s = src2[i];
        const int2 d = dst2[i];
        const f32x4 ts0 = tab[s.x];
        const f32x4 td0 = tab[d.x];
        const f32x4 ts1 = tab[s.y];
        const f32x4 td1 = tab[d.y];
        float2 r;
        r.x = edge_score(ts0, td0, w0, w1);
        r.y = edge_score(ts1, td1, w0, w1);
        out2[i] = r;
    }
    const int tail_base = n_half << 1;
    for (int e = tail_base + gid; e < n_edges; e += stride) {
        out[e] = edge_score(tab[src[e]], tab[dst[e]], w0, w1);
    }
}

extern "C" void kernel_launch(void* const* d_in, const int* in_sizes, int n_in,
                              void* d_out, int out_size, void* d_ws, size_t ws_size,
                              hipStream_t stream) {
    const float* W_b = (const float*)d_in[2];
    const float* W_p = (const float*)d_in[3];
    const float* a_b = (const float*)d_in[4];
    const float* a_p = (const float*)d_in[5];
    const float* g_b = (const float*)d_in[6];
    const float* g_p = (const float*)d_in[7];
    const int*   ei  = (const int*)d_in[8];     // [2, E] int32

    const int n_nodes = in_sizes[0] / 128;
    const int n_edges = in_sizes[8] / 2;

    const f32x4* zb4 = (const f32x4*)d_in[0];
    const f32x4* zp4 = (const f32x4*)d_in[1];
    const int*   src = ei;
    const int*   dst = ei + n_edges;
    float*       out = (float*)d_out;
    float*       tab = (float*)d_ws;            // n_nodes * 4 fp32

    void* args[] = {
        (void*)&W_b, (void*)&W_p, (void*)&a_b, (void*)&a_p,
        (void*)&zb4, (void*)&zp4, (void*)&src, (void*)&dst,
        (void*)&g_b, (void*)&g_p, (void*)&out, (void*)&tab,
        (void*)&n_nodes, (void*)&n_edges
    };

    // 1024 blocks x 256 thr; occupancy (VGPR<=64, 2KB LDS) = 8 blocks/CU
    // -> residency limit 2048 >> 1024. Checked; deterministic fallback.
    hipError_t err = hipLaunchCooperativeKernel((void*)coop_all_kernel,
                                                dim3(1024), dim3(256),
                                                args, 0, stream);
    if (err != hipSuccess) {
        (void)hipGetLastError();   // clear sticky error, take R12 path
        fused_node_kernel<<<512, 1024, 0, stream>>>(
            W_b, W_p, a_b, a_p, zb4, zp4, tab, n_nodes);
        const int n_half = n_edges >> 1;
        int eblocks = (n_half + 255) / 256;
        if (eblocks > 4096) eblocks = 4096;
        if (eblocks < 1) eblocks = 1;
        edge_scores_kernel<<<eblocks, 256, 0, stream>>>(
            src, dst, (const f32x4*)tab, g_b, g_p, out, n_edges);
    }
}

// Round 14
// 37.246 us; speedup vs baseline: 6.7520x; 6.7520x over previous
//
#include <hip/hip_runtime.h>
#include <hip/hip_bf16.h>

#define NEG_SLOPE 0.2f

typedef float f32x4 __attribute__((ext_vector_type(4)));

// ---------------------------------------------------------------------------
// Folded 64-lane reduction (6 shuffles) — proven R5.
// ---------------------------------------------------------------------------
__device__ __forceinline__ float fold_reduce(float sib, float sjb,
                                             float sip, float sjp,
                                             bool hiB, bool hiJ) {
    float g1 = hiB ? sib : sip;
    float r1 = __shfl_xor(g1, 16);
    float acc_i = (hiB ? sip : sib) + r1;
    float g2 = hiB ? sjb : sjp;
    float r2 = __shfl_xor(g2, 16);
    float acc_j = (hiB ? sjp : sjb) + r2;
    float g3 = hiJ ? acc_i : acc_j;
    float r3 = __shfl_xor(g3, 8);
    float acc = (hiJ ? acc_j : acc_i) + r3;
    acc += __shfl_xor(acc, 4);
    acc += __shfl_xor(acc, 2);
    acc += __shfl_xor(acc, 1);
    return acc;
}

__device__ __forceinline__ float dot4(const f32x4 z, const f32x4 v) {
    return z.x * v.x + z.y * v.y + z.z * v.z + z.w * v.w;
}

// ---------------------------------------------------------------------------
// Fused node kernel — EXACT R6 structure (measured best, 36.1 us total),
// single change: nontemporal hints on the 4 streaming z loads.
// 512 blocks x 1024 threads (2 blocks/CU), v-fold prologue in LDS,
// wave = 2 nodes/iter, 2-pair unroll, fp32 tab stores.
// ---------------------------------------------------------------------------
__global__ void __launch_bounds__(1024) fused_node_kernel(
        const float* __restrict__ W_b,
        const float* __restrict__ W_p,
        const float* __restrict__ a_b,
        const float* __restrict__ a_p,
        const f32x4* __restrict__ zb4,
        const f32x4* __restrict__ zp4,
        float*       __restrict__ tab,   // float view of [n_nodes][4]
        int n_nodes) {
    __shared__ float vsh[4][128];   // v1_b, v2_b, v1_p, v2_p
    __shared__ float psh[1024];

    const int tid = threadIdx.x;
    {   // prologue: vsh[vec][p] = sum_d W_ch[d][p] * a_ch[aoff + d]
        const int q   = tid >> 9;        // d-half (0: d<32, 1: d>=32)
        const int r   = tid & 511;       // output index (vec*128 + p)
        const int vec = r >> 7;
        const int p   = r & 127;
        const float* W = (vec >= 2) ? W_p : W_b;
        const float* a = ((vec >= 2) ? a_p : a_b) + (vec & 1) * 64 + 32 * q;
        const float* Wc = W + (32 * q) * 128 + p;
        float acc = 0.f;
        #pragma unroll
        for (int k = 0; k < 32; ++k)
            acc += Wc[k * 128] * a[k];
        psh[tid] = acc;
    }
    __syncthreads();
    if (tid < 512)
        vsh[tid >> 7][tid & 127] = psh[tid] + psh[512 + tid];
    __syncthreads();

    const int lane = tid & 63;
    const int h    = lane >> 5;                 // which node of the pair
    const int c    = lane & 31;                 // f32x4 column group
    const int wave   = (blockIdx.x * blockDim.x + tid) >> 6;
    const int nwaves = (gridDim.x * blockDim.x) >> 6;   // 8192
    const int npairs = (n_nodes + 1) >> 1;

    const f32x4 v1b = *reinterpret_cast<const f32x4*>(&vsh[0][4 * c]);
    const f32x4 v2b = *reinterpret_cast<const f32x4*>(&vsh[1][4 * c]);
    const f32x4 v1p = *reinterpret_cast<const f32x4*>(&vsh[2][4 * c]);
    const f32x4 v2p = *reinterpret_cast<const f32x4*>(&vsh[3][4 * c]);

    const bool hiB = (c & 16) != 0;
    const bool hiJ = (c & 8)  != 0;
    const bool wr  = (c & 7) == 0;
    const int  comp = c >> 3;

    for (int pr = wave; pr < npairs; pr += 2 * nwaves) {
        const int pr2 = pr + nwaves;
        int node1 = 2 * pr + h;
        const bool valid1 = node1 < n_nodes;
        if (!valid1) node1 = n_nodes - 1;
        const f32x4 zb1 = __builtin_nontemporal_load(&zb4[(size_t)node1 * 32 + c]);
        const f32x4 zp1 = __builtin_nontemporal_load(&zp4[(size_t)node1 * 32 + c]);
        int node2 = 2 * pr2 + h;
        const bool run2 = pr2 < npairs;
        bool valid2 = run2 && (node2 < n_nodes);
        if (!valid2) node2 = n_nodes - 1;
        const f32x4 zb2 = __builtin_nontemporal_load(&zb4[(size_t)node2 * 32 + c]);
        const f32x4 zp2 = __builtin_nontemporal_load(&zp4[(size_t)node2 * 32 + c]);

        float acc1 = fold_reduce(dot4(zb1, v1b), dot4(zb1, v2b),
                                 dot4(zp1, v1p), dot4(zp1, v2p), hiB, hiJ);
        if (wr && valid1) tab[(size_t)node1 * 4 + comp] = acc1;

        float acc2 = fold_reduce(dot4(zb2, v1b), dot4(zb2, v2b),
                                 dot4(zp2, v1p), dot4(zp2, v2p), hiB, hiJ);
        if (wr && valid2) tab[(size_t)node2 * 4 + comp] = acc2;
    }
}

// ---------------------------------------------------------------------------
// Edge kernel — EXACT R6 (2 edges/thread, fp32 float4 gathers).
// ---------------------------------------------------------------------------
__device__ __forceinline__ float lrelu(float x) {
    return x >= 0.f ? x : NEG_SLOPE * x;
}

__device__ __forceinline__ float edge_score(const f32x4 ts, const f32x4 td,
                                            float w0, float w1) {
    const float sb = 0.5f * (lrelu(ts.x + td.y) + lrelu(td.x + ts.y));
    const float sp = 0.5f * (lrelu(ts.z + td.w) + lrelu(td.z + ts.w));
    const float sc = w0 * sb + w1 * sp;            // TAU_MRF == 1
    return 1.f / (1.f + __expf(-sc));
}

__global__ void __launch_bounds__(256) edge_scores_kernel(
        const int*   __restrict__ src,
        const int*   __restrict__ dst,
        const f32x4* __restrict__ tab,
        const float* __restrict__ gamma_b,
        const float* __restrict__ gamma_p,
        float*       __restrict__ out,
        int n_edges) {
    const float gb = *gamma_b;
    const float gp = *gamma_p;
    const float w0 = 1.f / (1.f + __expf(gp - gb));  // softmax over 2 logits
    const float w1 = 1.f - w0;

    const int n_half = n_edges >> 1;
    const int stride = gridDim.x * blockDim.x;
    const int gid    = blockIdx.x * blockDim.x + threadIdx.x;

    const int2* src2 = (const int2*)src;
    const int2* dst2 = (const int2*)dst;
    float2*     out2 = (float2*)out;

    for (int i = gid; i < n_half; i += stride) {
        const int2 s = src2[i];
        const int2 d = dst2[i];
        const f32x4 ts0 = tab[s.x];
        const f32x4 td0 = tab[d.x];
        const f32x4 ts1 = tab[s.y];
        const f32x4 td1 = tab[d.y];
        float2 r;
        r.x = edge_score(ts0, td0, w0, w1);
        r.y = edge_score(ts1, td1, w0, w1);
        out2[i] = r;
    }
    const int tail_base = n_half << 1;
    for (int e = tail_base + gid; e < n_edges; e += stride) {
        out[e] = edge_score(tab[src[e]], tab[dst[e]], w0, w1);
    }
}

extern "C" void kernel_launch(void* const* d_in, const int* in_sizes, int n_in,
                              void* d_out, int out_size, void* d_ws, size_t ws_size,
                              hipStream_t stream) {
    const float* z_beh  = (const float*)d_in[0];
    const float* z_pref = (const float*)d_in[1];
    const float* W_b    = (const float*)d_in[2];
    const float* W_p    = (const float*)d_in[3];
    const float* a_b    = (const float*)d_in[4];
    const float* a_p    = (const float*)d_in[5];
    const float* g_b    = (const float*)d_in[6];
    const float* g_p    = (const float*)d_in[7];
    const int*   ei     = (const int*)d_in[8];   // [2, E] int32

    const int n_nodes = in_sizes[0] / 128;
    const int n_edges = in_sizes[8] / 2;

    float* tab = (float*)d_ws;                   // n_nodes * 4 floats

    // 512 blocks x 1024 threads: exactly resident, 8192 waves (R6-proven)
    fused_node_kernel<<<512, 1024, 0, stream>>>(
        W_b, W_p, a_b, a_p,
        (const f32x4*)z_beh, (const f32x4*)z_pref, tab, n_nodes);

    const int n_half = n_edges >> 1;
    int eblocks = (n_half + 255) / 256;
    if (eblocks > 4096) eblocks = 4096;
    if (eblocks < 1) eblocks = 1;
    edge_scores_kernel<<<eblocks, 256, 0, stream>>>(
        ei, ei + n_edges, (const f32x4*)tab, g_b, g_p, (float*)d_out, n_edges);
}